// Round 1
// baseline (181.877 us; speedup 1.0000x reference)
//
#include <hip/hip_runtime.h>

#define B_SZ   1024
#define OUT_SZ 512
#define IN_SZ  1024

#define BT 128            // b-tile per block
#define OT 64             // o-tile per block
#define KT 16             // k-step staged in LDS
#define KSPLIT 8
#define KC (IN_SZ / KSPLIT)   // 128 k per block

__global__ __launch_bounds__(256) void rbf_zero(float4* p, int n4) {
    int i = blockIdx.x * blockDim.x + threadIdx.x;
    if (i < n4) p[i] = make_float4(0.f, 0.f, 0.f, 0.f);
}

// z[b,o] += sum_k (u*(x-w))^2 over this block's K-slice
__global__ __launch_bounds__(256, 2) void rbf_main(
    const float* __restrict__ x, const float* __restrict__ w,
    const float* __restrict__ u, float* __restrict__ z)
{
    // +4 pad: keeps float4 alignment (row strides 132/68 are 16B multiples)
    // and rotates banks by 4 per k-row to kill staging write conflicts.
    __shared__ __align__(16) float xs[KT][BT + 4];
    __shared__ __align__(16) float us[KT][OT + 4];
    __shared__ __align__(16) float qs[KT][OT + 4];  // q = u*w

    const int t     = threadIdx.x;
    const int kk_s  = t & 15;     // staging: k index
    const int row_s = t >> 4;     // staging: row group 0..15

    const int bBase = blockIdx.x * BT;
    const int oBase = blockIdx.y * OT;
    const int kBase = blockIdx.z * KC;

    const int to = t & 15;        // compute: o-group (o frag = to*4 .. +4)
    const int tb = t >> 4;        // compute: b-group (b frag = tb*8 .. +8)

    float acc[8][4];
    #pragma unroll
    for (int i = 0; i < 8; ++i)
        #pragma unroll
        for (int j = 0; j < 4; ++j) acc[i][j] = 0.f;

    for (int kc = 0; kc < KC; kc += KT) {
        const int k0 = kBase + kc;

        // stage x: KT x BT (2048 elems, 8 per thread), i-contiguous global reads
        #pragma unroll
        for (int j = 0; j < 8; ++j) {
            int b_l = row_s + j * 16;
            xs[kk_s][b_l] = x[(size_t)(bBase + b_l) * IN_SZ + (k0 + kk_s)];
        }
        // stage u and q=u*w: KT x OT (1024 elems each, 4 per thread)
        #pragma unroll
        for (int j = 0; j < 4; ++j) {
            int o_l = row_s + j * 16;
            size_t gi = (size_t)(oBase + o_l) * IN_SZ + (k0 + kk_s);
            float uv = u[gi];
            float wv = w[gi];
            us[kk_s][o_l] = uv;
            qs[kk_s][o_l] = uv * wv;
        }
        __syncthreads();

        #pragma unroll
        for (int kk = 0; kk < KT; ++kk) {
            float4 xa = *(const float4*)&xs[kk][tb * 8];
            float4 xb = *(const float4*)&xs[kk][tb * 8 + 4];
            float4 uu = *(const float4*)&us[kk][to * 4];
            float4 qq = *(const float4*)&qs[kk][to * 4];
            float xv[8] = {xa.x, xa.y, xa.z, xa.w, xb.x, xb.y, xb.z, xb.w};
            float uv[4] = {uu.x, uu.y, uu.z, uu.w};
            float qv[4] = {qq.x, qq.y, qq.z, qq.w};
            #pragma unroll
            for (int i = 0; i < 8; ++i)
                #pragma unroll
                for (int j = 0; j < 4; ++j) {
                    float d = fmaf(uv[j], xv[i], -qv[j]);   // u*x - u*w
                    acc[i][j] = fmaf(d, d, acc[i][j]);
                }
        }
        __syncthreads();
    }

    // split-K partial accumulate into z (device-scope fp32 atomics)
    #pragma unroll
    for (int i = 0; i < 8; ++i) {
        int b = bBase + tb * 8 + i;
        #pragma unroll
        for (int j = 0; j < 4; ++j) {
            int o = oBase + to * 4 + j;
            atomicAdd(&z[(size_t)b * OUT_SZ + o], acc[i][j]);
        }
    }
}

// in-place: z -> y + a*(1-2y) = a + y*(1-2a)
__global__ __launch_bounds__(256) void rbf_epilogue(
    float* __restrict__ zio, const float* __restrict__ andor)
{
    int idx = blockIdx.x * blockDim.x + threadIdx.x;
    if (idx < B_SZ * OUT_SZ) {
        float a = andor[idx & (OUT_SZ - 1)];   // o = idx % OUT
        float zv = zio[idx];
        float y = __expf(-zv);
        zio[idx] = fmaf(y, 1.f - 2.f * a, a);
    }
}

extern "C" void kernel_launch(void* const* d_in, const int* in_sizes, int n_in,
                              void* d_out, int out_size, void* d_ws, size_t ws_size,
                              hipStream_t stream) {
    const float* x = (const float*)d_in[0];   // [B, IN]
    const float* w = (const float*)d_in[1];   // [OUT, IN]
    const float* u = (const float*)d_in[2];   // [OUT, IN]
    const float* a = (const float*)d_in[3];   // [1, OUT]
    float* out = (float*)d_out;               // [B, OUT]

    const int n = B_SZ * OUT_SZ;

    rbf_zero<<<dim3((n / 4 + 255) / 256), dim3(256), 0, stream>>>((float4*)out, n / 4);

    dim3 grid(B_SZ / BT, OUT_SZ / OT, KSPLIT);   // 8 x 8 x 8 = 512 blocks
    rbf_main<<<grid, dim3(256), 0, stream>>>(x, w, u, out);

    rbf_epilogue<<<dim3((n + 255) / 256), dim3(256), 0, stream>>>(out, a);
}